// Round 9
// baseline (296.622 us; speedup 1.0000x reference)
//
#include <hip/hip_runtime.h>
#include <hip/hip_bf16.h>

#define N_NODES 100000
#define N_EDGES 1600000
#define N_PAD   100096          // N rounded up to 128
#define BSHIFT  10              // 1024 nodes per bucket
#define NBUCKET 98              // ceil(N_NODES / 1024)
#define BCAP    19456           // per-bucket record capacity (mean 16327, +8 sigma)
#define EPB     4096            // edges per scatter block
#define NSCAT   391             // scatter blocks = ceil(E / EPB)
#define NGEMM1  1563            // gemm64 blocks = ceil((N+1)/64)
#define PCAP    34816           // per-bucket PADDED col capacity (mean 32775)
#define ZROW    N_NODES         // sentinel src: zero row in BOTH Y and Z spaces

__device__ __forceinline__ unsigned short f32_to_bf16(float f) {
    unsigned int u = __float_as_uint(f);
    unsigned int r = (u + 0x7fffu + ((u >> 16) & 1u)) >> 16;
    return (unsigned short)r;
}
__device__ __forceinline__ float bf16_lo(unsigned int p) {   // low 16 bits
    return __uint_as_float(p << 16);
}
__device__ __forceinline__ float bf16_hi(unsigned int p) {   // high 16 bits
    return __uint_as_float(p & 0xffff0000u);
}

// ---------- K1: fused scatter + gemm_n64 (independent work, one launch) ------
// Blocks [0,NSCAT): bucket scatter. Blocks [NSCAT,..): Y[M+1,64] = X @ W1
// (bf16 out, row M zeroed via <=M guard for gather1 pad sentinels).
__global__ void __launch_bounds__(256) k1_scatter_gemm64(
    const int* __restrict__ src, const int* __restrict__ dst,
    int* __restrict__ bcur, unsigned int* __restrict__ tmp,
    const float4* __restrict__ X4, const float* __restrict__ W,
    unsigned short* __restrict__ Y, int n_edges, int M) {
    extern __shared__ char smem[];
    int t = threadIdx.x;
    if (blockIdx.x < NSCAT) {
        int* lh = (int*)smem;            // 128-entry histogram / cursor
        int e0 = blockIdx.x * EPB;
        int e1 = min(e0 + EPB, n_edges);
        if (t < 128) lh[t] = 0;
        __syncthreads();
        int ls[16], ld[16];
        #pragma unroll
        for (int j = 0; j < 16; j++) {
            int e = e0 + t + j * 256;
            if (e < e1) {
                ls[j] = src[e];
                ld[j] = dst[e];
                atomicAdd(&lh[ld[j] >> BSHIFT], 1);
            }
        }
        __syncthreads();
        if (t < NBUCKET) {
            int c = lh[t];
            lh[t] = (c > 0) ? atomicAdd(&bcur[t], c) : 0;
        }
        __syncthreads();
        #pragma unroll
        for (int j = 0; j < 16; j++) {
            int e = e0 + t + j * 256;
            if (e < e1) {
                int b = ld[j] >> BSHIFT;
                int p = atomicAdd(&lh[b], 1);
                if (p < BCAP)
                    tmp[(size_t)b * BCAP + p] =
                        ((unsigned)ls[j] << BSHIFT) | (unsigned)(ld[j] & 1023);
            }
        }
        return;
    }
    // ---- gemm64 part ----
    float* sx = (float*)smem;            // [64][65]
    float* sw = sx + 64 * 65;            // [64*64]
    int base = (blockIdx.x - NSCAT) * 64;
    for (int i = t; i < 64 * 16; i += 256) {
        int r = i >> 4, c4 = i & 15;
        int row = base + r;
        float4 v = make_float4(0.f, 0.f, 0.f, 0.f);
        if (row < M) v = X4[(size_t)row * 16 + c4];
        sx[r * 65 + c4 * 4 + 0] = v.x; sx[r * 65 + c4 * 4 + 1] = v.y;
        sx[r * 65 + c4 * 4 + 2] = v.z; sx[r * 65 + c4 * 4 + 3] = v.w;
    }
    float4* sw4 = (float4*)sw;
    const float4* W4 = (const float4*)W;
    for (int i = t; i < 64 * 16; i += 256) sw4[i] = W4[i];
    __syncthreads();

    int tm = t & 15;
    int tn = t >> 4;
    float acc[4][4] = {{0.f}};
    #pragma unroll 8
    for (int k = 0; k < 64; k++) {
        float4 b = sw4[k * 16 + tn];
        float a0 = sx[(tm * 4 + 0) * 65 + k], a1 = sx[(tm * 4 + 1) * 65 + k];
        float a2 = sx[(tm * 4 + 2) * 65 + k], a3 = sx[(tm * 4 + 3) * 65 + k];
        acc[0][0] = fmaf(a0, b.x, acc[0][0]); acc[0][1] = fmaf(a0, b.y, acc[0][1]);
        acc[0][2] = fmaf(a0, b.z, acc[0][2]); acc[0][3] = fmaf(a0, b.w, acc[0][3]);
        acc[1][0] = fmaf(a1, b.x, acc[1][0]); acc[1][1] = fmaf(a1, b.y, acc[1][1]);
        acc[1][2] = fmaf(a1, b.z, acc[1][2]); acc[1][3] = fmaf(a1, b.w, acc[1][3]);
        acc[2][0] = fmaf(a2, b.x, acc[2][0]); acc[2][1] = fmaf(a2, b.y, acc[2][1]);
        acc[2][2] = fmaf(a2, b.z, acc[2][2]); acc[2][3] = fmaf(a2, b.w, acc[2][3]);
        acc[3][0] = fmaf(a3, b.x, acc[3][0]); acc[3][1] = fmaf(a3, b.y, acc[3][1]);
        acc[3][2] = fmaf(a3, b.z, acc[3][2]); acc[3][3] = fmaf(a3, b.w, acc[3][3]);
    }
    #pragma unroll
    for (int i = 0; i < 4; i++) {
        int row = base + tm * 4 + i;
        if (row <= M) {     // row == M: zero row (acc==0), feeds gather pads
            ushort4 p;
            p.x = f32_to_bf16(acc[i][0]); p.y = f32_to_bf16(acc[i][1]);
            p.z = f32_to_bf16(acc[i][2]); p.w = f32_to_bf16(acc[i][3]);
            *(ushort4*)&Y[(size_t)row * 64 + tn * 4] = p;
        }
    }
}

// ---------- per-bucket -> PADDED CSR (node lists padded to x32 with ZROW) ----
__global__ void __launch_bounds__(1024) bucket_to_csr(
    const unsigned int* __restrict__ tmp, const int* __restrict__ bcur,
    int2* __restrict__ meta, int* __restrict__ col, int n_nodes) {
    __shared__ int nh[1024];
    __shared__ int npref[1024];
    int b = blockIdx.x;
    int t = threadIdx.x;
    int m = min(bcur[b], BCAP);
    int cbase = b * PCAP;
    nh[t] = 0;
    __syncthreads();
    const unsigned int* te = tmp + (size_t)b * BCAP;
    for (int i = t; i < m; i += 1024) atomicAdd(&nh[te[i] & 1023], 1);
    __syncthreads();
    int d  = nh[t];
    int pc = (d + 31) & ~31;                // padded count (multiple of 32)
    npref[t] = pc;
    __syncthreads();
    for (int off = 1; off < 1024; off <<= 1) {
        int u = (t >= off) ? npref[t - off] : 0;
        __syncthreads();
        npref[t] += u;
        __syncthreads();
    }
    int begin = cbase + npref[t] - pc;      // exclusive prefix of padded counts
    int node = (b << BSHIFT) + t;
    if (node < n_nodes) meta[node] = make_int2(begin, d);
    for (int j = d; j < pc; j++) col[begin + j] = ZROW;   // sentinel pads
    nh[t] = begin;                          // repurpose as placement cursor
    __syncthreads();
    for (int i = t; i < m; i += 1024) {
        unsigned int e = te[i];
        int pos = atomicAdd(&nh[e & 1023], 1);
        col[pos] = (int)(e >> BSHIFT);
    }
}

// ---------- fused gather1 + W2: z2[n] = relu(mean_agg(y)[n]+b1) @ W2 ---------
// After the butterfly g-reduce, EVERY lane holds full h[8c..8c+7]. W2 columns
// live in 8 float4 registers per lane (constant across nodes, loaded once):
// z[4g+u] = sum_q h[8c+q]*W2[8c+q][4g+u], then 12-shfl c-reduce, bf16 store.
// Eliminates the h array (51MB traffic) and the gemm_n32 dispatch entirely.
__global__ void __launch_bounds__(256) gather1_fused(
    const uint4* __restrict__ Y4, const int2* __restrict__ meta,
    const int* __restrict__ col, const float* __restrict__ b1,
    const float* __restrict__ W2, unsigned short* __restrict__ Z,
    int n_nodes) {
    int lane = threadIdx.x & 63;
    int g = lane >> 3;          // edge subgroup 0..7 / output quad 4g..4g+3
    int c = lane & 7;           // 8-feature chunk 0..7
    // per-lane constants (independent of node)
    const float4* b1_4 = (const float4*)b1;
    float4 ba = b1_4[c * 2], bb = b1_4[c * 2 + 1];
    const float4* W2_4 = (const float4*)W2;     // [64][8] float4 view of [64][32]
    float4 wr[8];
    #pragma unroll
    for (int q = 0; q < 8; q++) wr[q] = W2_4[(8 * c + q) * 8 + g];

    int n = blockIdx.x * 4 + (threadIdx.x >> 6);
    if (n > n_nodes) return;
    if (n == n_nodes) {                      // zero row for gather2 pads
        if (c == 0) {
            ushort4 p = make_ushort4(0, 0, 0, 0);
            *(ushort4*)&Z[(size_t)n * 32 + 4 * g] = p;
        }
        return;
    }
    int2 md = meta[n];
    int beg = md.x;
    int d = md.y;

    float acc[8] = {0.f, 0.f, 0.f, 0.f, 0.f, 0.f, 0.f, 0.f};
    for (int i = 0; i < d; i += 32) {
        int s0 = col[beg + i + g];          // unconditional: pads are ZROW
        int s1 = col[beg + i + g + 8];
        int s2 = col[beg + i + g + 16];
        int s3 = col[beg + i + g + 24];
        uint4 v0 = Y4[(size_t)s0 * 8 + c];
        uint4 v1 = Y4[(size_t)s1 * 8 + c];
        uint4 v2 = Y4[(size_t)s2 * 8 + c];
        uint4 v3 = Y4[(size_t)s3 * 8 + c];
        acc[0] += (bf16_lo(v0.x) + bf16_lo(v1.x)) + (bf16_lo(v2.x) + bf16_lo(v3.x));
        acc[1] += (bf16_hi(v0.x) + bf16_hi(v1.x)) + (bf16_hi(v2.x) + bf16_hi(v3.x));
        acc[2] += (bf16_lo(v0.y) + bf16_lo(v1.y)) + (bf16_lo(v2.y) + bf16_lo(v3.y));
        acc[3] += (bf16_hi(v0.y) + bf16_hi(v1.y)) + (bf16_hi(v2.y) + bf16_hi(v3.y));
        acc[4] += (bf16_lo(v0.z) + bf16_lo(v1.z)) + (bf16_lo(v2.z) + bf16_lo(v3.z));
        acc[5] += (bf16_hi(v0.z) + bf16_hi(v1.z)) + (bf16_hi(v2.z) + bf16_hi(v3.z));
        acc[6] += (bf16_lo(v0.w) + bf16_lo(v1.w)) + (bf16_lo(v2.w) + bf16_lo(v3.w));
        acc[7] += (bf16_hi(v0.w) + bf16_hi(v1.w)) + (bf16_hi(v2.w) + bf16_hi(v3.w));
    }
    #pragma unroll
    for (int m = 8; m <= 32; m <<= 1) {      // butterfly: ALL lanes get full sums
        #pragma unroll
        for (int q = 0; q < 8; q++) acc[q] += __shfl_xor(acc[q], m);
    }
    float inv = 1.0f / fmaxf((float)d, 1.0f);
    float hv[8];
    hv[0] = fmaxf(fmaf(acc[0], inv, ba.x), 0.f);
    hv[1] = fmaxf(fmaf(acc[1], inv, ba.y), 0.f);
    hv[2] = fmaxf(fmaf(acc[2], inv, ba.z), 0.f);
    hv[3] = fmaxf(fmaf(acc[3], inv, ba.w), 0.f);
    hv[4] = fmaxf(fmaf(acc[4], inv, bb.x), 0.f);
    hv[5] = fmaxf(fmaf(acc[5], inv, bb.y), 0.f);
    hv[6] = fmaxf(fmaf(acc[6], inv, bb.z), 0.f);
    hv[7] = fmaxf(fmaf(acc[7], inv, bb.w), 0.f);
    float z0 = 0.f, z1 = 0.f, z2 = 0.f, z3 = 0.f;
    #pragma unroll
    for (int q = 0; q < 8; q++) {
        z0 = fmaf(hv[q], wr[q].x, z0);
        z1 = fmaf(hv[q], wr[q].y, z1);
        z2 = fmaf(hv[q], wr[q].z, z2);
        z3 = fmaf(hv[q], wr[q].w, z3);
    }
    #pragma unroll
    for (int m = 1; m <= 4; m <<= 1) {       // c-reduce: sum the 8 feature slices
        z0 += __shfl_xor(z0, m);
        z1 += __shfl_xor(z1, m);
        z2 += __shfl_xor(z2, m);
        z3 += __shfl_xor(z3, m);
    }
    if (c == 0) {
        ushort4 p;
        p.x = f32_to_bf16(z0); p.y = f32_to_bf16(z1);
        p.z = f32_to_bf16(z2); p.w = f32_to_bf16(z3);
        *(ushort4*)&Z[(size_t)n * 32 + 4 * g] = p;   // feats 4g..4g+3
    }
}

// ---------- gather2: out[n] = sigmoid(mean_f(relu(mean_agg(z2)[n]+b2))*Wd+bd) --
// Restructured: c in 0..7 (uint2 loads), g in 0..7 -> epilogue is 12+3 shfl
// (was 32+2), the dominant cost at avg degree 16.
__global__ void __launch_bounds__(256) gather_final32(
    const uint2* __restrict__ Z2, const int2* __restrict__ meta,
    const int* __restrict__ col, const float* __restrict__ b2,
    const float* __restrict__ Wd, const float* __restrict__ bd,
    float* __restrict__ out, int n_nodes) {
    int n = blockIdx.x * 4 + (threadIdx.x >> 6);
    if (n >= n_nodes) return;
    int lane = threadIdx.x & 63;
    int g = lane >> 3;          // edge subgroup 0..7
    int c = lane & 7;           // 4-feature chunk 0..7
    int2 md = meta[n];
    int beg = md.x;
    int d = md.y;

    float a0 = 0.f, a1 = 0.f, a2 = 0.f, a3 = 0.f;
    for (int i = 0; i < d; i += 32) {
        int s0 = col[beg + i + g];          // unconditional: pads are ZROW
        int s1 = col[beg + i + g + 8];
        int s2 = col[beg + i + g + 16];
        int s3 = col[beg + i + g + 24];
        uint2 v0 = Z2[(size_t)s0 * 8 + c];
        uint2 v1 = Z2[(size_t)s1 * 8 + c];
        uint2 v2 = Z2[(size_t)s2 * 8 + c];
        uint2 v3 = Z2[(size_t)s3 * 8 + c];
        a0 += (bf16_lo(v0.x) + bf16_lo(v1.x)) + (bf16_lo(v2.x) + bf16_lo(v3.x));
        a1 += (bf16_hi(v0.x) + bf16_hi(v1.x)) + (bf16_hi(v2.x) + bf16_hi(v3.x));
        a2 += (bf16_lo(v0.y) + bf16_lo(v1.y)) + (bf16_lo(v2.y) + bf16_lo(v3.y));
        a3 += (bf16_hi(v0.y) + bf16_hi(v1.y)) + (bf16_hi(v2.y) + bf16_hi(v3.y));
    }
    #pragma unroll
    for (int m = 8; m <= 32; m <<= 1) {
        a0 += __shfl_xor(a0, m);
        a1 += __shfl_xor(a1, m);
        a2 += __shfl_xor(a2, m);
        a3 += __shfl_xor(a3, m);
    }
    float inv = 1.0f / fmaxf((float)d, 1.0f);
    const float4* b2_4 = (const float4*)b2;
    float4 ba = b2_4[c];                    // b2[4c..4c+3]
    float local = fmaxf(fmaf(a0, inv, ba.x), 0.f)
                + fmaxf(fmaf(a1, inv, ba.y), 0.f)
                + fmaxf(fmaf(a2, inv, ba.z), 0.f)
                + fmaxf(fmaf(a3, inv, ba.w), 0.f);
    local += __shfl_xor(local, 1);
    local += __shfl_xor(local, 2);
    local += __shfl_xor(local, 4);
    if (lane == 0) {
        float z = fmaf(local * (1.0f / 32.0f), Wd[0], bd[0]);
        out[n] = 1.0f / (1.0f + __expf(-z));
    }
}

extern "C" void kernel_launch(void* const* d_in, const int* in_sizes, int n_in,
                              void* d_out, int out_size, void* d_ws, size_t ws_size,
                              hipStream_t stream) {
    const float* x    = (const float*)d_in[0];   // [N,64]
    const int*   esrc = (const int*)d_in[1];     // [E]
    const int*   edst = (const int*)d_in[2];     // [E]
    const float* W1   = (const float*)d_in[3];   // [64,64]
    const float* b1   = (const float*)d_in[4];   // [64]
    const float* W2   = (const float*)d_in[5];   // [64,32]
    const float* b2   = (const float*)d_in[6];   // [32]
    const float* Wd   = (const float*)d_in[7];   // [1,1]
    const float* bd   = (const float*)d_in[8];   // [1]
    float* out = (float*)d_out;                  // [N,1]

    // workspace (~41.3 MB), h array ELIMINATED:
    //   bcur[128] meta[int2 x N_PAD] col[NBUCKET*PCAP + 1024] (13.7MB)
    //   tmp uint[NBUCKET*BCAP] (7.6MB)
    //   y bf16[(N+1)*64] (12.8MB, row N = zero row)
    //   z2 bf16[(N+1)*32] (6.4MB, row N = zero row)
    int*  bcur = (int*)d_ws;
    int2* meta = (int2*)(bcur + 128);
    int*  col  = (int*)(meta + N_PAD);
    unsigned int* tmp = (unsigned int*)(col + (size_t)NBUCKET * PCAP + 1024);
    unsigned short* y  = (unsigned short*)(tmp + (size_t)NBUCKET * BCAP);
    unsigned short* z2 = y + (size_t)(N_NODES + 1) * 64;

    hipMemsetAsync((void*)bcur, 0, 128 * sizeof(int), stream);

    // K1: scatter (391 blocks) + y = x@W1 incl. zero row (1563 blocks), fused
    k1_scatter_gemm64<<<NSCAT + NGEMM1, 256, 33024, stream>>>(
        esrc, edst, bcur, tmp, (const float4*)x, W1, y, N_EDGES, N_NODES);
    // padded CSR (x32 node lists, ZROW sentinels)
    bucket_to_csr<<<NBUCKET, 1024, 0, stream>>>(tmp, bcur, meta, col, N_NODES);
    // z2 = relu(mean_agg(y)+b1) @ W2  — fused, h never materialized.
    // Grid covers node N_NODES to emit the z2 zero row.
    gather1_fused<<<(N_NODES + 1 + 3) / 4, 256, 0, stream>>>(
        (const uint4*)y, meta, col, b1, W2, z2, N_NODES);
    // out = sigmoid(mean(relu(mean_agg(z2) + b2)) * Wd + bd)
    gather_final32<<<(N_NODES + 3) / 4, 256, 0, stream>>>(
        (const uint2*)z2, meta, col, b2, Wd, bd, out, N_NODES);
}

// Round 10
// 235.204 us; speedup vs baseline: 1.2611x; 1.2611x over previous
//
#include <hip/hip_runtime.h>
#include <hip/hip_bf16.h>

#define N_NODES 100000
#define N_EDGES 1600000
#define N_PAD   100096          // N rounded up to 128
#define BSHIFT  10              // 1024 nodes per bucket
#define NBUCKET 98              // ceil(N_NODES / 1024)
#define BCAP    19456           // per-bucket record capacity (mean 16327, +8 sigma)
#define EPB     4096            // edges per scatter block
#define NSCAT   391             // scatter blocks = ceil(E / EPB)
#define NGEMM1  1563            // gemm64 blocks = ceil((N+1)/64)
#define PCAP    34816           // per-bucket PADDED col capacity (mean 32775)
#define ZROW    N_NODES         // sentinel src: zero row in BOTH Y and Z spaces

__device__ __forceinline__ unsigned short f32_to_bf16(float f) {
    unsigned int u = __float_as_uint(f);
    unsigned int r = (u + 0x7fffu + ((u >> 16) & 1u)) >> 16;
    return (unsigned short)r;
}
__device__ __forceinline__ float bf16_lo(unsigned int p) {   // low 16 bits
    return __uint_as_float(p << 16);
}
__device__ __forceinline__ float bf16_hi(unsigned int p) {   // high 16 bits
    return __uint_as_float(p & 0xffff0000u);
}

// ---------- K1: fused scatter + gemm_n64 (independent work, one launch) ------
// Blocks [0,NSCAT): bucket scatter. Blocks [NSCAT,..): Y[M+1,64] = X @ W1
// (bf16 out, row M zeroed via <=M guard for gather1 pad sentinels).
__global__ void __launch_bounds__(256) k1_scatter_gemm64(
    const int* __restrict__ src, const int* __restrict__ dst,
    int* __restrict__ bcur, unsigned int* __restrict__ tmp,
    const float4* __restrict__ X4, const float* __restrict__ W,
    unsigned short* __restrict__ Y, int n_edges, int M) {
    extern __shared__ char smem[];
    int t = threadIdx.x;
    if (blockIdx.x < NSCAT) {
        int* lh = (int*)smem;            // 128-entry histogram / cursor
        int e0 = blockIdx.x * EPB;
        int e1 = min(e0 + EPB, n_edges);
        if (t < 128) lh[t] = 0;
        __syncthreads();
        int ls[16], ld[16];
        #pragma unroll
        for (int j = 0; j < 16; j++) {
            int e = e0 + t + j * 256;
            if (e < e1) {
                ls[j] = src[e];
                ld[j] = dst[e];
                atomicAdd(&lh[ld[j] >> BSHIFT], 1);
            }
        }
        __syncthreads();
        if (t < NBUCKET) {
            int c = lh[t];
            lh[t] = (c > 0) ? atomicAdd(&bcur[t], c) : 0;
        }
        __syncthreads();
        #pragma unroll
        for (int j = 0; j < 16; j++) {
            int e = e0 + t + j * 256;
            if (e < e1) {
                int b = ld[j] >> BSHIFT;
                int p = atomicAdd(&lh[b], 1);
                if (p < BCAP)
                    tmp[(size_t)b * BCAP + p] =
                        ((unsigned)ls[j] << BSHIFT) | (unsigned)(ld[j] & 1023);
            }
        }
        return;
    }
    // ---- gemm64 part ----
    float* sx = (float*)smem;            // [64][65]
    float* sw = sx + 64 * 65;            // [64*64]
    int base = (blockIdx.x - NSCAT) * 64;
    for (int i = t; i < 64 * 16; i += 256) {
        int r = i >> 4, c4 = i & 15;
        int row = base + r;
        float4 v = make_float4(0.f, 0.f, 0.f, 0.f);
        if (row < M) v = X4[(size_t)row * 16 + c4];
        sx[r * 65 + c4 * 4 + 0] = v.x; sx[r * 65 + c4 * 4 + 1] = v.y;
        sx[r * 65 + c4 * 4 + 2] = v.z; sx[r * 65 + c4 * 4 + 3] = v.w;
    }
    float4* sw4 = (float4*)sw;
    const float4* W4 = (const float4*)W;
    for (int i = t; i < 64 * 16; i += 256) sw4[i] = W4[i];
    __syncthreads();

    int tm = t & 15;
    int tn = t >> 4;
    float acc[4][4] = {{0.f}};
    #pragma unroll 8
    for (int k = 0; k < 64; k++) {
        float4 b = sw4[k * 16 + tn];
        float a0 = sx[(tm * 4 + 0) * 65 + k], a1 = sx[(tm * 4 + 1) * 65 + k];
        float a2 = sx[(tm * 4 + 2) * 65 + k], a3 = sx[(tm * 4 + 3) * 65 + k];
        acc[0][0] = fmaf(a0, b.x, acc[0][0]); acc[0][1] = fmaf(a0, b.y, acc[0][1]);
        acc[0][2] = fmaf(a0, b.z, acc[0][2]); acc[0][3] = fmaf(a0, b.w, acc[0][3]);
        acc[1][0] = fmaf(a1, b.x, acc[1][0]); acc[1][1] = fmaf(a1, b.y, acc[1][1]);
        acc[1][2] = fmaf(a1, b.z, acc[1][2]); acc[1][3] = fmaf(a1, b.w, acc[1][3]);
        acc[2][0] = fmaf(a2, b.x, acc[2][0]); acc[2][1] = fmaf(a2, b.y, acc[2][1]);
        acc[2][2] = fmaf(a2, b.z, acc[2][2]); acc[2][3] = fmaf(a2, b.w, acc[2][3]);
        acc[3][0] = fmaf(a3, b.x, acc[3][0]); acc[3][1] = fmaf(a3, b.y, acc[3][1]);
        acc[3][2] = fmaf(a3, b.z, acc[3][2]); acc[3][3] = fmaf(a3, b.w, acc[3][3]);
    }
    #pragma unroll
    for (int i = 0; i < 4; i++) {
        int row = base + tm * 4 + i;
        if (row <= M) {     // row == M: zero row (acc==0), feeds gather pads
            ushort4 p;
            p.x = f32_to_bf16(acc[i][0]); p.y = f32_to_bf16(acc[i][1]);
            p.z = f32_to_bf16(acc[i][2]); p.w = f32_to_bf16(acc[i][3]);
            *(ushort4*)&Y[(size_t)row * 64 + tn * 4] = p;
        }
    }
}

// ---------- per-bucket -> PADDED CSR (node lists padded to x32 with ZROW) ----
__global__ void __launch_bounds__(1024) bucket_to_csr(
    const unsigned int* __restrict__ tmp, const int* __restrict__ bcur,
    int2* __restrict__ meta, int* __restrict__ col, int n_nodes) {
    __shared__ int nh[1024];
    __shared__ int npref[1024];
    int b = blockIdx.x;
    int t = threadIdx.x;
    int m = min(bcur[b], BCAP);
    int cbase = b * PCAP;
    nh[t] = 0;
    __syncthreads();
    const unsigned int* te = tmp + (size_t)b * BCAP;
    for (int i = t; i < m; i += 1024) atomicAdd(&nh[te[i] & 1023], 1);
    __syncthreads();
    int d  = nh[t];
    int pc = (d + 31) & ~31;                // padded count (multiple of 32)
    npref[t] = pc;
    __syncthreads();
    for (int off = 1; off < 1024; off <<= 1) {
        int u = (t >= off) ? npref[t - off] : 0;
        __syncthreads();
        npref[t] += u;
        __syncthreads();
    }
    int begin = cbase + npref[t] - pc;      // exclusive prefix of padded counts
    int node = (b << BSHIFT) + t;
    if (node < n_nodes) meta[node] = make_int2(begin, d);
    for (int j = d; j < pc; j++) col[begin + j] = ZROW;   // sentinel pads
    nh[t] = begin;                          // repurpose as placement cursor
    __syncthreads();
    for (int i = t; i < m; i += 1024) {
        unsigned int e = te[i];
        int pos = atomicAdd(&nh[e & 1023], 1);
        col[pos] = (int)(e >> BSHIFT);
    }
}

// ---------- dense GEMM: Z[M+1,32] = H[M,64] @ W[64,32] (row M zeroed) --------
__global__ void __launch_bounds__(256) gemm_n32(const float4* __restrict__ X4,
                                                const float* __restrict__ W,
                                                unsigned short* __restrict__ Z, int M) {
    __shared__ float sx[128][65];
    __shared__ float sw[64 * 32];
    int t = threadIdx.x;
    int base = blockIdx.x * 128;
    for (int i = t; i < 128 * 16; i += 256) {
        int r = i >> 4, c4 = i & 15;
        int row = base + r;
        float4 v = make_float4(0.f, 0.f, 0.f, 0.f);
        if (row < M) v = X4[(size_t)row * 16 + c4];
        sx[r][c4 * 4 + 0] = v.x; sx[r][c4 * 4 + 1] = v.y;
        sx[r][c4 * 4 + 2] = v.z; sx[r][c4 * 4 + 3] = v.w;
    }
    float4* sw4 = (float4*)sw;
    const float4* W4 = (const float4*)W;
    for (int i = t; i < 64 * 8; i += 256) sw4[i] = W4[i];
    __syncthreads();

    int tm = t & 31;
    int tn = t >> 5;
    float acc[4][4] = {{0.f}};
    #pragma unroll 8
    for (int k = 0; k < 64; k++) {
        float4 b = sw4[k * 8 + tn];
        float a0 = sx[tm * 4 + 0][k], a1 = sx[tm * 4 + 1][k];
        float a2 = sx[tm * 4 + 2][k], a3 = sx[tm * 4 + 3][k];
        acc[0][0] = fmaf(a0, b.x, acc[0][0]); acc[0][1] = fmaf(a0, b.y, acc[0][1]);
        acc[0][2] = fmaf(a0, b.z, acc[0][2]); acc[0][3] = fmaf(a0, b.w, acc[0][3]);
        acc[1][0] = fmaf(a1, b.x, acc[1][0]); acc[1][1] = fmaf(a1, b.y, acc[1][1]);
        acc[1][2] = fmaf(a1, b.z, acc[1][2]); acc[1][3] = fmaf(a1, b.w, acc[1][3]);
        acc[2][0] = fmaf(a2, b.x, acc[2][0]); acc[2][1] = fmaf(a2, b.y, acc[2][1]);
        acc[2][2] = fmaf(a2, b.z, acc[2][2]); acc[2][3] = fmaf(a2, b.w, acc[2][3]);
        acc[3][0] = fmaf(a3, b.x, acc[3][0]); acc[3][1] = fmaf(a3, b.y, acc[3][1]);
        acc[3][2] = fmaf(a3, b.z, acc[3][2]); acc[3][3] = fmaf(a3, b.w, acc[3][3]);
    }
    #pragma unroll
    for (int i = 0; i < 4; i++) {
        int row = base + tm * 4 + i;
        if (row <= M) {     // row == M: zero row for gather2 pads
            ushort4 p;
            p.x = f32_to_bf16(acc[i][0]); p.y = f32_to_bf16(acc[i][1]);
            p.z = f32_to_bf16(acc[i][2]); p.w = f32_to_bf16(acc[i][3]);
            *(ushort4*)&Z[(size_t)row * 32 + tn * 4] = p;
        }
    }
}

// ---------- gather1: h[n] = relu(mean_{s in N(n)} y[s] + b1) -----------------
// col is padded to x32 with ZROW -> NO clamp/select per slot: pure load chain.
// (R8 version, measured good. R9's W2-register fusion regressed 3x: compiler
// sinks the epilogue-only W2 loads past the edge loop, serializing them with
// the shfl chain at wave end. Do not re-fuse without pinning evidence.)
__global__ void __launch_bounds__(256) gather_relu64(
    const uint4* __restrict__ Y4, const int2* __restrict__ meta,
    const int* __restrict__ col, const float* __restrict__ b1,
    float4* __restrict__ H4, int n_nodes) {
    int n = blockIdx.x * 4 + (threadIdx.x >> 6);
    if (n >= n_nodes) return;
    int lane = threadIdx.x & 63;
    int g = lane >> 3;          // edge subgroup 0..7
    int c = lane & 7;           // 8-feature chunk 0..7
    int2 md = meta[n];
    int beg = md.x;
    int d = md.y;

    float acc[8] = {0.f, 0.f, 0.f, 0.f, 0.f, 0.f, 0.f, 0.f};
    for (int i = 0; i < d; i += 32) {
        int s0 = col[beg + i + g];          // unconditional: pads are ZROW
        int s1 = col[beg + i + g + 8];
        int s2 = col[beg + i + g + 16];
        int s3 = col[beg + i + g + 24];
        uint4 v0 = Y4[(size_t)s0 * 8 + c];
        uint4 v1 = Y4[(size_t)s1 * 8 + c];
        uint4 v2 = Y4[(size_t)s2 * 8 + c];
        uint4 v3 = Y4[(size_t)s3 * 8 + c];
        acc[0] += (bf16_lo(v0.x) + bf16_lo(v1.x)) + (bf16_lo(v2.x) + bf16_lo(v3.x));
        acc[1] += (bf16_hi(v0.x) + bf16_hi(v1.x)) + (bf16_hi(v2.x) + bf16_hi(v3.x));
        acc[2] += (bf16_lo(v0.y) + bf16_lo(v1.y)) + (bf16_lo(v2.y) + bf16_lo(v3.y));
        acc[3] += (bf16_hi(v0.y) + bf16_hi(v1.y)) + (bf16_hi(v2.y) + bf16_hi(v3.y));
        acc[4] += (bf16_lo(v0.z) + bf16_lo(v1.z)) + (bf16_lo(v2.z) + bf16_lo(v3.z));
        acc[5] += (bf16_hi(v0.z) + bf16_hi(v1.z)) + (bf16_hi(v2.z) + bf16_hi(v3.z));
        acc[6] += (bf16_lo(v0.w) + bf16_lo(v1.w)) + (bf16_lo(v2.w) + bf16_lo(v3.w));
        acc[7] += (bf16_hi(v0.w) + bf16_hi(v1.w)) + (bf16_hi(v2.w) + bf16_hi(v3.w));
    }
    #pragma unroll
    for (int m = 8; m <= 32; m <<= 1) {
        #pragma unroll
        for (int q = 0; q < 8; q++) acc[q] += __shfl_xor(acc[q], m);
    }
    float inv = 1.0f / fmaxf((float)d, 1.0f);
    const float4* b1_4 = (const float4*)b1;
    float4 ba = b1_4[c * 2], bb = b1_4[c * 2 + 1];
    if (g == 0) {
        float4 o0, o1;
        o0.x = fmaxf(fmaf(acc[0], inv, ba.x), 0.f);
        o0.y = fmaxf(fmaf(acc[1], inv, ba.y), 0.f);
        o0.z = fmaxf(fmaf(acc[2], inv, ba.z), 0.f);
        o0.w = fmaxf(fmaf(acc[3], inv, ba.w), 0.f);
        o1.x = fmaxf(fmaf(acc[4], inv, bb.x), 0.f);
        o1.y = fmaxf(fmaf(acc[5], inv, bb.y), 0.f);
        o1.z = fmaxf(fmaf(acc[6], inv, bb.z), 0.f);
        o1.w = fmaxf(fmaf(acc[7], inv, bb.w), 0.f);
        H4[(size_t)n * 16 + c * 2]     = o0;
        H4[(size_t)n * 16 + c * 2 + 1] = o1;
    }
}

// ---------- gather2: out[n] = sigmoid(mean_f(relu(mean_agg(z2)[n]+b2))*Wd+bd) --
// Restructured (from R9, kept): c in 0..7 (uint2 loads), g in 0..7 -> epilogue
// is 12+3 shfl (was 32+2), the dominant cost at avg degree 16. Load coalescing
// unchanged: 8 lanes x 8B = 64B per record.
__global__ void __launch_bounds__(256) gather_final32(
    const uint2* __restrict__ Z2, const int2* __restrict__ meta,
    const int* __restrict__ col, const float* __restrict__ b2,
    const float* __restrict__ Wd, const float* __restrict__ bd,
    float* __restrict__ out, int n_nodes) {
    int n = blockIdx.x * 4 + (threadIdx.x >> 6);
    if (n >= n_nodes) return;
    int lane = threadIdx.x & 63;
    int g = lane >> 3;          // edge subgroup 0..7
    int c = lane & 7;           // 4-feature chunk 0..7
    int2 md = meta[n];
    int beg = md.x;
    int d = md.y;

    float a0 = 0.f, a1 = 0.f, a2 = 0.f, a3 = 0.f;
    for (int i = 0; i < d; i += 32) {
        int s0 = col[beg + i + g];          // unconditional: pads are ZROW
        int s1 = col[beg + i + g + 8];
        int s2 = col[beg + i + g + 16];
        int s3 = col[beg + i + g + 24];
        uint2 v0 = Z2[(size_t)s0 * 8 + c];
        uint2 v1 = Z2[(size_t)s1 * 8 + c];
        uint2 v2 = Z2[(size_t)s2 * 8 + c];
        uint2 v3 = Z2[(size_t)s3 * 8 + c];
        a0 += (bf16_lo(v0.x) + bf16_lo(v1.x)) + (bf16_lo(v2.x) + bf16_lo(v3.x));
        a1 += (bf16_hi(v0.x) + bf16_hi(v1.x)) + (bf16_hi(v2.x) + bf16_hi(v3.x));
        a2 += (bf16_lo(v0.y) + bf16_lo(v1.y)) + (bf16_lo(v2.y) + bf16_lo(v3.y));
        a3 += (bf16_hi(v0.y) + bf16_hi(v1.y)) + (bf16_hi(v2.y) + bf16_hi(v3.y));
    }
    #pragma unroll
    for (int m = 8; m <= 32; m <<= 1) {
        a0 += __shfl_xor(a0, m);
        a1 += __shfl_xor(a1, m);
        a2 += __shfl_xor(a2, m);
        a3 += __shfl_xor(a3, m);
    }
    float inv = 1.0f / fmaxf((float)d, 1.0f);
    const float4* b2_4 = (const float4*)b2;
    float4 ba = b2_4[c];                    // b2[4c..4c+3]
    float local = fmaxf(fmaf(a0, inv, ba.x), 0.f)
                + fmaxf(fmaf(a1, inv, ba.y), 0.f)
                + fmaxf(fmaf(a2, inv, ba.z), 0.f)
                + fmaxf(fmaf(a3, inv, ba.w), 0.f);
    local += __shfl_xor(local, 1);
    local += __shfl_xor(local, 2);
    local += __shfl_xor(local, 4);
    if (lane == 0) {
        float z = fmaf(local * (1.0f / 32.0f), Wd[0], bd[0]);
        out[n] = 1.0f / (1.0f + __expf(-z));
    }
}

extern "C" void kernel_launch(void* const* d_in, const int* in_sizes, int n_in,
                              void* d_out, int out_size, void* d_ws, size_t ws_size,
                              hipStream_t stream) {
    const float* x    = (const float*)d_in[0];   // [N,64]
    const int*   esrc = (const int*)d_in[1];     // [E]
    const int*   edst = (const int*)d_in[2];     // [E]
    const float* W1   = (const float*)d_in[3];   // [64,64]
    const float* b1   = (const float*)d_in[4];   // [64]
    const float* W2   = (const float*)d_in[5];   // [64,32]
    const float* b2   = (const float*)d_in[6];   // [32]
    const float* Wd   = (const float*)d_in[7];   // [1,1]
    const float* bd   = (const float*)d_in[8];   // [1]
    float* out = (float*)d_out;                  // [N,1]

    // workspace (~59.3 MB), R8 layout:
    //   bcur[128] meta[int2 x N_PAD] col[NBUCKET*PCAP + 1024] (13.7MB)
    //   | union{ h f32[N*64] (25.6MB), tmp uint[NBUCKET*BCAP] (7.6MB) }
    //   | y bf16[(N+1)*64] (12.8MB, row N = zero row)
    //   | z2 bf16[(N+1)*32] (6.4MB, row N = zero row)
    int*  bcur = (int*)d_ws;
    int2* meta = (int2*)(bcur + 128);
    int*  col  = (int*)(meta + N_PAD);
    float* h   = (float*)(col + (size_t)NBUCKET * PCAP + 1024);
    unsigned int* tmp = (unsigned int*)h;        // aliases h (dead until gather1)
    unsigned short* y  = (unsigned short*)(h + (size_t)N_NODES * 64);
    unsigned short* z2 = y + (size_t)(N_NODES + 1) * 64;

    hipMemsetAsync((void*)bcur, 0, 128 * sizeof(int), stream);

    // K1: scatter (391 blocks) + y = x@W1 incl. zero row (1563 blocks), fused
    k1_scatter_gemm64<<<NSCAT + NGEMM1, 256, 33024, stream>>>(
        esrc, edst, bcur, tmp, (const float4*)x, W1, y, N_EDGES, N_NODES);
    // padded CSR (x32 node lists, ZROW sentinels)
    bucket_to_csr<<<NBUCKET, 1024, 0, stream>>>(tmp, bcur, meta, col, N_NODES);
    // h = relu(mean_agg(y) + b1)   (h overwrites tmp, which is dead now)
    gather_relu64<<<(N_NODES + 3) / 4, 256, 0, stream>>>(
        (const uint4*)y, meta, col, b1, (float4*)h, N_NODES);
    // z2 = h @ W2 incl. zero row
    gemm_n32<<<(N_NODES + 127) / 128, 256, 0, stream>>>((const float4*)h, W2, z2, N_NODES);
    // out = sigmoid(mean(relu(mean_agg(z2) + b2)) * Wd + bd)
    gather_final32<<<(N_NODES + 3) / 4, 256, 0, stream>>>(
        (const uint2*)z2, meta, col, b2, Wd, bd, out, N_NODES);
}